// Round 1
// baseline (1877.597 us; speedup 1.0000x reference)
//
#include <hip/hip_runtime.h>

// Problem constants
constexpr int B  = 2;
constexpr int S  = 1025;
constexpr int D  = 768;
constexpr int H  = 12;
constexpr int HD = 64;
constexpr int NM = 4;          // num masks
constexpr int ROWS = B * S;    // 2050
constexpr int BSD  = B * S * D;          // 1,574,400
constexpr int OUT_NEWH_OFF = BSD;                    // 1,574,400
constexpr int OUT_IDX_OFF  = BSD + NM * BSD;         // 7,872,000
constexpr int OUT_NEWX_OFF = OUT_IDX_OFF + B * NM;   // 7,872,008

// ---------------------------------------------------------------------------
// Kernel 1: fused QKV projection.  Q/K/V[row][j] = sum_k x[row][k]*W[j][k] + b[j]
// Tiles: 64 rows x 64 cols, K-step 16. 256 threads, each computes 4x4 per matrix.
// ---------------------------------------------------------------------------
__global__ __launch_bounds__(256) void qkv_proj_kernel(
    const float* __restrict__ x,
    const float* __restrict__ Wq, const float* __restrict__ bq,
    const float* __restrict__ Wk, const float* __restrict__ bk,
    const float* __restrict__ Wv, const float* __restrict__ bv,
    float* __restrict__ Q, float* __restrict__ K, float* __restrict__ V)
{
    __shared__ float Xs[16][65];
    __shared__ float Ws[3][16][65];

    const int tid  = threadIdx.x;
    const int row0 = blockIdx.x * 64;
    const int col0 = blockIdx.y * 64;
    const int tx = tid & 15;        // 0..15 (cols)
    const int ty = tid >> 4;        // 0..15 (rows)

    // loader mapping: thread loads one float4: r = tid>>2 (0..63), k-offset = (tid&3)*4
    const int lr = tid >> 2;
    const int lk = (tid & 3) * 4;

    float acc[3][4][4] = {};

    for (int k0 = 0; k0 < D; k0 += 16) {
        // X tile (64 rows x 16 k), transposed into Xs[k][row]
        {
            const int gr = row0 + lr;
            float4 xv = make_float4(0.f, 0.f, 0.f, 0.f);
            if (gr < ROWS) xv = *(const float4*)(x + (size_t)gr * D + k0 + lk);
            Xs[lk + 0][lr] = xv.x; Xs[lk + 1][lr] = xv.y;
            Xs[lk + 2][lr] = xv.z; Xs[lk + 3][lr] = xv.w;
        }
        // W tiles: j = col0 + lr (cols always in range; D % 64 == 0)
        {
            const int gj = col0 + lr;
            float4 wv;
            wv = *(const float4*)(Wq + (size_t)gj * D + k0 + lk);
            Ws[0][lk + 0][lr] = wv.x; Ws[0][lk + 1][lr] = wv.y;
            Ws[0][lk + 2][lr] = wv.z; Ws[0][lk + 3][lr] = wv.w;
            wv = *(const float4*)(Wk + (size_t)gj * D + k0 + lk);
            Ws[1][lk + 0][lr] = wv.x; Ws[1][lk + 1][lr] = wv.y;
            Ws[1][lk + 2][lr] = wv.z; Ws[1][lk + 3][lr] = wv.w;
            wv = *(const float4*)(Wv + (size_t)gj * D + k0 + lk);
            Ws[2][lk + 0][lr] = wv.x; Ws[2][lk + 1][lr] = wv.y;
            Ws[2][lk + 2][lr] = wv.z; Ws[2][lk + 3][lr] = wv.w;
        }
        __syncthreads();

        #pragma unroll
        for (int k = 0; k < 16; k++) {
            float a[4];
            #pragma unroll
            for (int i = 0; i < 4; i++) a[i] = Xs[k][ty * 4 + i];
            #pragma unroll
            for (int mt = 0; mt < 3; mt++) {
                float bb[4];
                #pragma unroll
                for (int j = 0; j < 4; j++) bb[j] = Ws[mt][k][tx * 4 + j];
                #pragma unroll
                for (int i = 0; i < 4; i++)
                    #pragma unroll
                    for (int j = 0; j < 4; j++)
                        acc[mt][i][j] += a[i] * bb[j];
            }
        }
        __syncthreads();
    }

    // store
    #pragma unroll
    for (int i = 0; i < 4; i++) {
        const int gr = row0 + ty * 4 + i;
        if (gr >= ROWS) continue;
        #pragma unroll
        for (int j = 0; j < 4; j++) {
            const int gc = col0 + tx * 4 + j;
            Q[(size_t)gr * D + gc] = acc[0][i][j] + bq[gc];
            K[(size_t)gr * D + gc] = acc[1][i][j] + bk[gc];
            V[(size_t)gr * D + gc] = acc[2][i][j] + bv[gc];
        }
    }
}

// ---------------------------------------------------------------------------
// Kernel 2: attention. One block per (q-row, head, batch).
// Scores computed once; 5 softmax variants (base + 4 masks); one PV pass
// accumulating all 5 so V is read once.
// ---------------------------------------------------------------------------
__global__ __launch_bounds__(256) void attn_kernel(
    const float* __restrict__ Q, const float* __restrict__ K,
    const float* __restrict__ V, const int* __restrict__ masks,
    float* __restrict__ out_h, float* __restrict__ out_newh)
{
    __shared__ float s_q[HD];
    __shared__ float s_s[S];          // raw scaled scores
    __shared__ float s_p[5][S];       // softmax numerators per variant
    __shared__ float s_pv[4][HD];
    __shared__ float s_red[4];

    const int tid  = threadIdx.x;
    const int qi   = blockIdx.x;
    const int hh   = blockIdx.y;
    const int b    = blockIdx.z;
    const int lane = tid & 63;
    const int wv   = tid >> 6;      // wave id 0..3
    const int g    = wv;            // PV key-group
    const int dd   = lane;          // PV dim

    // stage q row
    if (tid < HD) s_q[tid] = Q[((size_t)(b * S + qi)) * D + hh * HD + tid];
    __syncthreads();

    // scores
    for (int k = tid; k < S; k += 256) {
        const float4* k4 = (const float4*)(K + ((size_t)(b * S + k)) * D + hh * HD);
        float acc = 0.f;
        #pragma unroll
        for (int i = 0; i < 16; i++) {
            float4 kv = k4[i];
            acc += s_q[4 * i + 0] * kv.x + s_q[4 * i + 1] * kv.y
                 + s_q[4 * i + 2] * kv.z + s_q[4 * i + 3] * kv.w;
        }
        s_s[k] = acc * 0.125f;   // 1/sqrt(64)
    }
    __syncthreads();

    float inv[5];

    for (int t = 0; t < 5; t++) {
        const int* mrow = (t > 0) ? (masks + ((size_t)(b * NM + (t - 1))) * (S - 1)) : nullptr;

        // --- max ---
        float lm = -1e30f;
        for (int k = tid; k < S; k += 256) {
            float val = s_s[k];
            if (t > 0 && k > 0 && mrow[k - 1] == 0) val -= 10000.f;
            lm = fmaxf(lm, val);
        }
        #pragma unroll
        for (int o = 32; o > 0; o >>= 1) lm = fmaxf(lm, __shfl_down(lm, o));
        if (lane == 0) s_red[wv] = lm;
        __syncthreads();
        const float mx = fmaxf(fmaxf(s_red[0], s_red[1]), fmaxf(s_red[2], s_red[3]));
        __syncthreads();

        // --- exp + sum ---
        float ls = 0.f;
        for (int k = tid; k < S; k += 256) {
            float val = s_s[k];
            if (t > 0 && k > 0 && mrow[k - 1] == 0) val -= 10000.f;
            float p = __expf(val - mx);
            s_p[t][k] = p;
            ls += p;
        }
        #pragma unroll
        for (int o = 32; o > 0; o >>= 1) ls += __shfl_down(ls, o);
        if (lane == 0) s_red[wv] = ls;
        __syncthreads();
        inv[t] = 1.0f / (s_red[0] + s_red[1] + s_red[2] + s_red[3]);
        __syncthreads();
    }

    // --- single PV pass for all 5 variants ---
    float acc[5] = {0.f, 0.f, 0.f, 0.f, 0.f};
    const float* vbase = V + (size_t)b * S * D + hh * HD + dd;
    for (int k = g; k < S; k += 4) {
        const float vvv = vbase[(size_t)k * D];
        #pragma unroll
        for (int t = 0; t < 5; t++) acc[t] += s_p[t][k] * vvv;
    }

    for (int t = 0; t < 5; t++) {
        s_pv[g][dd] = acc[t];
        __syncthreads();
        if (tid < HD) {
            const float o = (s_pv[0][tid] + s_pv[1][tid] + s_pv[2][tid] + s_pv[3][tid]) * inv[t];
            if (t == 0)
                out_h[((size_t)(b * S + qi)) * D + hh * HD + tid] = o;
            else
                out_newh[((size_t)((b * NM + (t - 1)) * S + qi)) * D + hh * HD + tid] = o;
        }
        __syncthreads();
    }
}

// ---------------------------------------------------------------------------
// Kernel 3: new_x broadcast copy + img_idx
// ---------------------------------------------------------------------------
__global__ __launch_bounds__(256) void tail_kernel(
    const float* __restrict__ x, float* __restrict__ out_newx,
    float* __restrict__ out_idx)
{
    const int SLAB4  = S * D / 4;        // 196,800 float4 per (b,m) slab
    const int TOTAL4 = B * NM * SLAB4;   // 1,574,400
    const float4* x4 = (const float4*)x;
    float4* o4 = (float4*)out_newx;
    for (int f = blockIdx.x * blockDim.x + threadIdx.x; f < TOTAL4;
         f += gridDim.x * blockDim.x) {
        const int bm  = f / SLAB4;
        const int rem = f - bm * SLAB4;
        o4[f] = x4[(bm >> 2) * SLAB4 + rem];
    }
    const int idx = blockIdx.x * blockDim.x + threadIdx.x;
    if (idx < B * NM) out_idx[idx] = (float)(idx >> 2);  // repeat(arange(B), M)
}

// ---------------------------------------------------------------------------
extern "C" void kernel_launch(void* const* d_in, const int* in_sizes, int n_in,
                              void* d_out, int out_size, void* d_ws, size_t ws_size,
                              hipStream_t stream)
{
    const float* x     = (const float*)d_in[0];
    const int*   masks = (const int*)  d_in[1];
    const float* Wq    = (const float*)d_in[2];
    const float* bq    = (const float*)d_in[3];
    const float* Wk    = (const float*)d_in[4];
    const float* bk    = (const float*)d_in[5];
    const float* Wv    = (const float*)d_in[6];
    const float* bv    = (const float*)d_in[7];

    float* out = (float*)d_out;
    float* out_h    = out;
    float* out_newh = out + OUT_NEWH_OFF;
    float* out_idx  = out + OUT_IDX_OFF;
    float* out_newx = out + OUT_NEWX_OFF;

    float* Qw = (float*)d_ws;
    float* Kw = Qw + BSD;
    float* Vw = Kw + BSD;

    // 1. QKV projection
    {
        dim3 grid((ROWS + 63) / 64, D / 64);
        qkv_proj_kernel<<<grid, 256, 0, stream>>>(x, Wq, bq, Wk, bk, Wv, bv,
                                                  Qw, Kw, Vw);
    }
    // 2. attention (base + 4 mask variants)
    {
        dim3 grid(S, H, B);
        attn_kernel<<<grid, 256, 0, stream>>>(Qw, Kw, Vw, masks, out_h, out_newh);
    }
    // 3. new_x copy + img_idx
    {
        tail_kernel<<<2048, 256, 0, stream>>>(x, out_newx, out_idx);
    }
}

// Round 2
// 647.218 us; speedup vs baseline: 2.9010x; 2.9010x over previous
//
#include <hip/hip_runtime.h>

// Problem constants
constexpr int B  = 2;
constexpr int S  = 1025;
constexpr int D  = 768;
constexpr int H  = 12;
constexpr int HD = 64;
constexpr int NM = 4;          // num masks
constexpr int ROWS = B * S;    // 2050
constexpr int BSD  = B * S * D;          // 1,574,400
constexpr int OUT_NEWH_OFF = BSD;                    // 1,574,400
constexpr int OUT_IDX_OFF  = BSD + NM * BSD;         // 7,872,000
constexpr int OUT_NEWX_OFF = OUT_IDX_OFF + B * NM;   // 7,872,008

constexpr int QB  = 16;                   // q rows per block
constexpr int KT  = 64;                   // keys per tile
constexpr int NT  = (S + KT - 1) / KT;    // 17
constexpr int NQT = (S + QB - 1) / QB;    // 65

// ---------------------------------------------------------------------------
// Kernel 1: fused QKV projection (unchanged from round 1; ~2% of runtime)
// ---------------------------------------------------------------------------
__global__ __launch_bounds__(256) void qkv_proj_kernel(
    const float* __restrict__ x,
    const float* __restrict__ Wq, const float* __restrict__ bq,
    const float* __restrict__ Wk, const float* __restrict__ bk,
    const float* __restrict__ Wv, const float* __restrict__ bv,
    float* __restrict__ Q, float* __restrict__ K, float* __restrict__ V)
{
    __shared__ float Xs[16][65];
    __shared__ float Ws[3][16][65];

    const int tid  = threadIdx.x;
    const int row0 = blockIdx.x * 64;
    const int col0 = blockIdx.y * 64;
    const int tx = tid & 15;
    const int ty = tid >> 4;
    const int lr = tid >> 2;
    const int lk = (tid & 3) * 4;

    float acc[3][4][4] = {};

    for (int k0 = 0; k0 < D; k0 += 16) {
        {
            const int gr = row0 + lr;
            float4 xv = make_float4(0.f, 0.f, 0.f, 0.f);
            if (gr < ROWS) xv = *(const float4*)(x + (size_t)gr * D + k0 + lk);
            Xs[lk + 0][lr] = xv.x; Xs[lk + 1][lr] = xv.y;
            Xs[lk + 2][lr] = xv.z; Xs[lk + 3][lr] = xv.w;
        }
        {
            const int gj = col0 + lr;
            float4 wv;
            wv = *(const float4*)(Wq + (size_t)gj * D + k0 + lk);
            Ws[0][lk + 0][lr] = wv.x; Ws[0][lk + 1][lr] = wv.y;
            Ws[0][lk + 2][lr] = wv.z; Ws[0][lk + 3][lr] = wv.w;
            wv = *(const float4*)(Wk + (size_t)gj * D + k0 + lk);
            Ws[1][lk + 0][lr] = wv.x; Ws[1][lk + 1][lr] = wv.y;
            Ws[1][lk + 2][lr] = wv.z; Ws[1][lk + 3][lr] = wv.w;
            wv = *(const float4*)(Wv + (size_t)gj * D + k0 + lk);
            Ws[2][lk + 0][lr] = wv.x; Ws[2][lk + 1][lr] = wv.y;
            Ws[2][lk + 2][lr] = wv.z; Ws[2][lk + 3][lr] = wv.w;
        }
        __syncthreads();

        #pragma unroll
        for (int k = 0; k < 16; k++) {
            float a[4];
            #pragma unroll
            for (int i = 0; i < 4; i++) a[i] = Xs[k][ty * 4 + i];
            #pragma unroll
            for (int mt = 0; mt < 3; mt++) {
                float bb[4];
                #pragma unroll
                for (int j = 0; j < 4; j++) bb[j] = Ws[mt][k][tx * 4 + j];
                #pragma unroll
                for (int i = 0; i < 4; i++)
                    #pragma unroll
                    for (int j = 0; j < 4; j++)
                        acc[mt][i][j] += a[i] * bb[j];
            }
        }
        __syncthreads();
    }

    #pragma unroll
    for (int i = 0; i < 4; i++) {
        const int gr = row0 + ty * 4 + i;
        if (gr >= ROWS) continue;
        #pragma unroll
        for (int j = 0; j < 4; j++) {
            const int gc = col0 + tx * 4 + j;
            Q[(size_t)gr * D + gc] = acc[0][i][j] + bq[gc];
            K[(size_t)gr * D + gc] = acc[1][i][j] + bk[gc];
            V[(size_t)gr * D + gc] = acc[2][i][j] + bv[gc];
        }
    }
}

// ---------------------------------------------------------------------------
// Kernel 2: streaming attention. Block = (16 q-rows, head, batch).
// Single pass over key tiles: stage K/V/masks -> scores -> shared exp ->
// 5 masked sums + 5 masked PV accumulators in registers. No max pass
// (scores bounded), no S*S materialization, V read once per block.
// Thread role: tq = t>>4 (q-row 0..15), tk = t&15.
//   score phase: keys tk*4..tk*4+3   |   PV phase: dims tk*4..tk*4+3
// ---------------------------------------------------------------------------
__global__ __launch_bounds__(256) void attn_kernel(
    const float* __restrict__ Q, const float* __restrict__ K,
    const float* __restrict__ V, const int* __restrict__ masks,
    float* __restrict__ out_h, float* __restrict__ out_newh)
{
    // K chunks XOR-swizzled: chunk c of row r stored at chunk c ^ ((r>>2)&15)
    __shared__ float  Kl[KT][68];
    __shared__ float  Vl[KT][68];
    __shared__ float  Ql[QB][68];
    __shared__ float  El[QB][68];
    __shared__ float4 Ml[KT];
    __shared__ float  Ssum[5][QB];

    const int t  = threadIdx.x;
    const int qt = blockIdx.x;
    const int hh = blockIdx.y;
    const int b  = blockIdx.z;
    const int q0 = qt * QB;
    const int tq = t >> 4;
    const int tk = t & 15;

    // stage Q tile once (zeros for padded rows)
    {
        const int r = t >> 4, c = t & 15;
        float4 qv = make_float4(0.f, 0.f, 0.f, 0.f);
        if (q0 + r < S)
            qv = *(const float4*)(Q + ((size_t)(b * S + q0 + r)) * D + hh * HD + c * 4);
        *(float4*)&Ql[r][c * 4] = qv;
    }

    float acc[5][4];
    #pragma unroll
    for (int a = 0; a < 5; a++)
        #pragma unroll
        for (int j = 0; j < 4; j++) acc[a][j] = 0.f;
    float sums[5] = {0.f, 0.f, 0.f, 0.f, 0.f};

    for (int i = 0; i < NT; ++i) {
        const int k0 = i * KT;
        __syncthreads();   // previous tile's PV done (and Q staged, first iter)

        // ---- stage K (swizzled), V (linear), masks ----
        #pragma unroll
        for (int it = 0; it < 4; ++it) {
            const int idx = t + it * 256;
            const int r = idx >> 4, c = idx & 15;
            const int p = k0 + r;
            float4 kv = make_float4(0.f, 0.f, 0.f, 0.f);
            float4 vv = kv;
            if (p < S) {
                const size_t off = ((size_t)(b * S + p)) * D + hh * HD + c * 4;
                kv = *(const float4*)(K + off);
                vv = *(const float4*)(V + off);
            }
            const int cK = c ^ ((r >> 2) & 15);
            *(float4*)&Kl[r][cK * 4] = kv;
            *(float4*)&Vl[r][c * 4]  = vv;
        }
        if (t < KT) {
            const int p = k0 + t;
            float4 mv = make_float4(0.f, 0.f, 0.f, 0.f);
            if (p >= 1 && p < S) {
                const int mi = p - 1;
                mv.x = (float)masks[((size_t)(b * NM + 0)) * (S - 1) + mi];
                mv.y = (float)masks[((size_t)(b * NM + 1)) * (S - 1) + mi];
                mv.z = (float)masks[((size_t)(b * NM + 2)) * (S - 1) + mi];
                mv.w = (float)masks[((size_t)(b * NM + 3)) * (S - 1) + mi];
            }
            Ml[t] = mv;
        }
        __syncthreads();

        // ---- scores + exp for keys tk*4..+3 of q-row tq ----
        float sc[4] = {0.f, 0.f, 0.f, 0.f};
        #pragma unroll
        for (int c = 0; c < 16; ++c) {
            const float4 qv = *(const float4*)&Ql[tq][c * 4];
            const int cc = (c ^ tk) * 4;
            #pragma unroll
            for (int j = 0; j < 4; ++j) {
                const float4 kv = *(const float4*)&Kl[tk * 4 + j][cc];
                sc[j] += qv.x * kv.x + qv.y * kv.y + qv.z * kv.z + qv.w * kv.w;
            }
        }
        float e[4];
        #pragma unroll
        for (int j = 0; j < 4; ++j) {
            const int p = k0 + tk * 4 + j;
            e[j] = (p < S) ? __expf(sc[j] * 0.125f) : 0.f;
        }
        *(float4*)&El[tq][tk * 4] = make_float4(e[0], e[1], e[2], e[3]);
        #pragma unroll
        for (int j = 0; j < 4; ++j) {
            const float4 mv = Ml[tk * 4 + j];
            sums[0] += e[j];
            sums[1] += mv.x * e[j];
            sums[2] += mv.y * e[j];
            sums[3] += mv.z * e[j];
            sums[4] += mv.w * e[j];
        }
        __syncthreads();

        // ---- PV: accumulate 5 variants for (q-row tq, dims tk*4..+3) ----
        #pragma unroll 4
        for (int kc = 0; kc < 16; ++kc) {
            const float4 e4 = *(const float4*)&El[tq][kc * 4];
            const float ee[4] = {e4.x, e4.y, e4.z, e4.w};
            #pragma unroll
            for (int j = 0; j < 4; ++j) {
                const int k = kc * 4 + j;
                const float4 vv = *(const float4*)&Vl[k][tk * 4];
                const float4 mv = Ml[k];
                const float ev = ee[j];
                const float w1 = mv.x * ev, w2 = mv.y * ev;
                const float w3 = mv.z * ev, w4 = mv.w * ev;
                acc[0][0] += ev * vv.x; acc[0][1] += ev * vv.y;
                acc[0][2] += ev * vv.z; acc[0][3] += ev * vv.w;
                acc[1][0] += w1 * vv.x; acc[1][1] += w1 * vv.y;
                acc[1][2] += w1 * vv.z; acc[1][3] += w1 * vv.w;
                acc[2][0] += w2 * vv.x; acc[2][1] += w2 * vv.y;
                acc[2][2] += w2 * vv.z; acc[2][3] += w2 * vv.w;
                acc[3][0] += w3 * vv.x; acc[3][1] += w3 * vv.y;
                acc[3][2] += w3 * vv.z; acc[3][3] += w3 * vv.w;
                acc[4][0] += w4 * vv.x; acc[4][1] += w4 * vv.y;
                acc[4][2] += w4 * vv.z; acc[4][3] += w4 * vv.w;
            }
        }
    }

    // ---- reduce per-q sums across the 16 tk lanes (within-wave butterfly) ----
    #pragma unroll
    for (int m = 1; m < 16; m <<= 1) {
        #pragma unroll
        for (int v2 = 0; v2 < 5; ++v2) sums[v2] += __shfl_xor(sums[v2], m);
    }
    if (tk < 5) Ssum[tk][tq] = sums[tk];
    __syncthreads();

    // ---- normalize + store ----
    const int q = q0 + tq;
    if (q < S) {
        #pragma unroll
        for (int v2 = 0; v2 < 5; ++v2) {
            const float inv = 1.0f / Ssum[v2][tq];
            float4 o;
            o.x = acc[v2][0] * inv; o.y = acc[v2][1] * inv;
            o.z = acc[v2][2] * inv; o.w = acc[v2][3] * inv;
            float* dst = (v2 == 0)
                ? out_h    + ((size_t)(b * S + q)) * D + hh * HD + tk * 4
                : out_newh + ((size_t)((b * NM + (v2 - 1)) * S + q)) * D + hh * HD + tk * 4;
            *(float4*)dst = o;
        }
    }
}

// ---------------------------------------------------------------------------
// Kernel 3: new_x broadcast copy + img_idx
// ---------------------------------------------------------------------------
__global__ __launch_bounds__(256) void tail_kernel(
    const float* __restrict__ x, float* __restrict__ out_newx,
    float* __restrict__ out_idx)
{
    const int SLAB4  = S * D / 4;
    const int TOTAL4 = B * NM * SLAB4;
    const float4* x4 = (const float4*)x;
    float4* o4 = (float4*)out_newx;
    for (int f = blockIdx.x * blockDim.x + threadIdx.x; f < TOTAL4;
         f += gridDim.x * blockDim.x) {
        const int bm  = f / SLAB4;
        const int rem = f - bm * SLAB4;
        o4[f] = x4[(bm >> 2) * SLAB4 + rem];
    }
    const int idx = blockIdx.x * blockDim.x + threadIdx.x;
    if (idx < B * NM) out_idx[idx] = (float)(idx >> 2);
}

// ---------------------------------------------------------------------------
extern "C" void kernel_launch(void* const* d_in, const int* in_sizes, int n_in,
                              void* d_out, int out_size, void* d_ws, size_t ws_size,
                              hipStream_t stream)
{
    const float* x     = (const float*)d_in[0];
    const int*   masks = (const int*)  d_in[1];
    const float* Wq    = (const float*)d_in[2];
    const float* bq    = (const float*)d_in[3];
    const float* Wk    = (const float*)d_in[4];
    const float* bk    = (const float*)d_in[5];
    const float* Wv    = (const float*)d_in[6];
    const float* bv    = (const float*)d_in[7];

    float* out = (float*)d_out;
    float* out_h    = out;
    float* out_newh = out + OUT_NEWH_OFF;
    float* out_idx  = out + OUT_IDX_OFF;
    float* out_newx = out + OUT_NEWX_OFF;

    float* Qw = (float*)d_ws;
    float* Kw = Qw + BSD;
    float* Vw = Kw + BSD;

    {
        dim3 grid((ROWS + 63) / 64, D / 64);
        qkv_proj_kernel<<<grid, 256, 0, stream>>>(x, Wq, bq, Wk, bk, Wv, bv,
                                                  Qw, Kw, Vw);
    }
    {
        dim3 grid(NQT, H, B);
        attn_kernel<<<grid, 256, 0, stream>>>(Qw, Kw, Vw, masks, out_h, out_newh);
    }
    {
        tail_kernel<<<2048, 256, 0, stream>>>(x, out_newx, out_idx);
    }
}

// Round 3
// 100.349 us; speedup vs baseline: 18.7107x; 6.4497x over previous
//
#include <hip/hip_runtime.h>

typedef float f32x4 __attribute__((ext_vector_type(4)));
typedef short s16x8 __attribute__((ext_vector_type(8)));

constexpr int B  = 2;
constexpr int S  = 1025;
constexpr int D  = 768;
constexpr int H  = 12;
constexpr int NM = 4;
constexpr int ROWS = B * S;              // 2050
constexpr int BSD  = B * S * D;          // 1,574,400
constexpr int SP   = 1088;               // padded S for Vt rows (16B-aligned rows)
constexpr int OUT_NEWH_OFF = BSD;
constexpr int OUT_IDX_OFF  = BSD + NM * BSD;
constexpr int OUT_NEWX_OFF = OUT_IDX_OFF + B * NM;

__device__ __forceinline__ unsigned short f2bf(float f) {
    unsigned u = __builtin_bit_cast(unsigned, f);
    u += 0x7FFF + ((u >> 16) & 1);          // RTNE (no NaN inputs here)
    return (unsigned short)(u >> 16);
}

// ---------------------------------------------------------------------------
// Kernel 1: QKV projection as bf16 MFMA GEMM.
// Grid (33 row-tiles of 64, 36 = 12 col-tiles x 3 matrices). 4 waves/block,
// each wave owns 16 rows x 64 cols. K-loop 768 in steps of 64.
// Outputs: Qb, Kb bf16 row-major [token][768]; V stored TRANSPOSED:
// Vt[((b*H+h)*64+d)*SP + s] so attention can stage it coalesced.
// LDS tiles chunk-XOR swizzled (16B chunk c of row r stored at c^(r&7)).
// ---------------------------------------------------------------------------
__global__ __launch_bounds__(256, 2) void qkv_mfma_kernel(
    const float* __restrict__ x,
    const float* __restrict__ Wq, const float* __restrict__ bq,
    const float* __restrict__ Wk, const float* __restrict__ bk,
    const float* __restrict__ Wv, const float* __restrict__ bv,
    unsigned short* __restrict__ Qb, unsigned short* __restrict__ Kb,
    unsigned short* __restrict__ Vt)
{
    __shared__ unsigned short Xs[64 * 64];
    __shared__ unsigned short Wl[64 * 64];

    const int t = threadIdx.x;
    const int row0 = blockIdx.x * 64;
    const int yy = blockIdx.y;
    const int mt = yy / 12;
    const int col0 = (yy % 12) * 64;
    const float* W    = (mt == 0) ? Wq : (mt == 1) ? Wk : Wv;
    const float* bias = (mt == 0) ? bq : (mt == 1) ? bk : bv;

    const int w = t >> 6, l = t & 63, lq = l & 15, grp = l >> 4;

    f32x4 acc[4] = {};

    for (int k0 = 0; k0 < D; k0 += 64) {
        __syncthreads();
        #pragma unroll
        for (int st = 0; st < 2; ++st) {
            const int cid = t + st * 256;
            const int r = cid >> 3, c = cid & 7;
            {   // X tile (rows = tokens)
                const int row = row0 + r;
                s16x8 v = {};
                if (row < ROWS) {
                    const float* p = x + (size_t)row * D + k0 + c * 8;
                    #pragma unroll
                    for (int i = 0; i < 8; i++) v[i] = (short)f2bf(p[i]);
                }
                *(s16x8*)&Xs[r * 64 + ((c ^ (r & 7)) * 8)] = v;
            }
            {   // W tile (rows = output cols)
                const float* p = W + (size_t)(col0 + r) * D + k0 + c * 8;
                s16x8 v;
                #pragma unroll
                for (int i = 0; i < 8; i++) v[i] = (short)f2bf(p[i]);
                *(s16x8*)&Wl[r * 64 + ((c ^ (r & 7)) * 8)] = v;
            }
        }
        __syncthreads();

        s16x8 a[2];
        const int xr = w * 16 + lq;
        #pragma unroll
        for (int kh = 0; kh < 2; ++kh)
            a[kh] = *(const s16x8*)&Xs[xr * 64 + (((kh * 4 + grp) ^ (lq & 7)) * 8)];
        #pragma unroll
        for (int nt = 0; nt < 4; ++nt) {
            const int wr = nt * 16 + lq;
            #pragma unroll
            for (int kh = 0; kh < 2; ++kh) {
                s16x8 bfr = *(const s16x8*)&Wl[wr * 64 + (((kh * 4 + grp) ^ (lq & 7)) * 8)];
                acc[nt] = __builtin_amdgcn_mfma_f32_16x16x32_bf16(a[kh], bfr, acc[nt], 0, 0, 0);
            }
        }
    }

    // epilogue: bias add, bf16 store (V transposed)
    #pragma unroll
    for (int nt = 0; nt < 4; ++nt) {
        const int col = col0 + nt * 16 + lq;
        const float bv_ = bias[col];
        #pragma unroll
        for (int r = 0; r < 4; ++r) {
            const int row = row0 + w * 16 + grp * 4 + r;   // C row = (l>>4)*4+reg
            if (row >= ROWS) continue;
            const unsigned short val = f2bf(acc[nt][r] + bv_);
            if (mt == 0)      Qb[(size_t)row * D + col] = val;
            else if (mt == 1) Kb[(size_t)row * D + col] = val;
            else {
                const int bb = (row >= S) ? 1 : 0;
                const int s  = row - bb * S;
                const int hh = col >> 6, dd = col & 63;
                Vt[((size_t)((bb * H + hh) * 64 + dd)) * SP + s] = val;
            }
        }
    }
}

// zero the Vt padding columns s in [S, SP) so attention never multiplies poison
__global__ void vt_pad_kernel(unsigned short* __restrict__ Vt)
{
    const int NPADC = SP - S;                 // 63
    const int NPAD = B * H * 64 * NPADC;      // 96768
    const int i = blockIdx.x * 256 + threadIdx.x;
    if (i < NPAD) {
        const int row = i / NPADC;
        const int s = S + (i % NPADC);
        Vt[(size_t)row * SP + s] = 0;
    }
}

// ---------------------------------------------------------------------------
// Kernel 2: MFMA attention. Block = (64 q-rows, head, batch), 4 waves x 16 q.
// Per 64-key tile: stage K (row-major) + V (d-major from Vt) into swizzled
// LDS -> QK^T (8 MFMA/wave) -> exp + 5 masked sums -> P to LDS bf16 ->
// PV (40 MFMA/wave: 5 variants x 4 d-tiles x 2 k-halves). Masked P-fragments
// are bitwise AND with 0xFFFF/0 masks. No max-subtraction (scores bounded).
// ---------------------------------------------------------------------------
__global__ __launch_bounds__(256, 2) void attn_mfma_kernel(
    const unsigned short* __restrict__ Qb, const unsigned short* __restrict__ Kb,
    const unsigned short* __restrict__ Vt, const int* __restrict__ masks,
    float* __restrict__ out_h, float* __restrict__ out_newh)
{
    __shared__ unsigned short Kl[64 * 64];
    __shared__ unsigned short Vl[64 * 64];     // rows = d, cols = k
    __shared__ unsigned short Pl[4 * 16 * 64]; // per-wave P tiles
    __shared__ float          Mf[4][64];
    __shared__ unsigned short Mm[4 * 64];

    const int t = threadIdx.x;
    const int qt = blockIdx.x, hh = blockIdx.y, b = blockIdx.z;
    const int q0 = qt * 64;
    const int w = t >> 6, l = t & 63, lq = l & 15, grp = l >> 4;

    // preload Q fragments (A-operand, rows = wave's 16 q)
    s16x8 qf[2] = {};
    {
        const int row = q0 + w * 16 + lq;
        if (row < S) {
            const unsigned short* p = Qb + (size_t)(b * S + row) * D + hh * 64 + grp * 8;
            qf[0] = *(const s16x8*)(p);
            qf[1] = *(const s16x8*)(p + 32);
        }
    }

    f32x4 acc[5][4] = {};
    float sums[5][4] = {};

    const int NT = 17;
    for (int it = 0; it < NT; ++it) {
        const int k0 = it * 64;
        __syncthreads();   // previous PV done before restage
        #pragma unroll
        for (int st = 0; st < 2; ++st) {
            const int cid = t + st * 256;
            const int r = cid >> 3, c = cid & 7;
            {   // K rows = keys
                const int p = k0 + r;
                uint4 v = make_uint4(0, 0, 0, 0);
                if (p < S) v = *(const uint4*)(Kb + (size_t)(b * S + p) * D + hh * 64 + c * 8);
                *(uint4*)&Kl[r * 64 + ((c ^ (r & 7)) * 8)] = v;
            }
            {   // V rows = dims (pad region pre-zeroed)
                uint4 v = *(const uint4*)(Vt + ((size_t)((b * H + hh) * 64 + r)) * SP + k0 + c * 8);
                *(uint4*)&Vl[r * 64 + ((c ^ (r & 7)) * 8)] = v;
            }
        }
        if (t < 64) {
            const int p = k0 + t;
            #pragma unroll
            for (int v = 0; v < 4; ++v) {
                const int m = (p >= 1 && p < S) ? masks[(size_t)(b * NM + v) * (S - 1) + p - 1] : 0;
                Mf[v][t] = (float)m;
                Mm[v * 64 + t] = m ? 0xFFFFu : 0u;
            }
        }
        __syncthreads();

        // ---- QK^T ----
        f32x4 qk[4] = {};
        #pragma unroll
        for (int kt = 0; kt < 4; ++kt) {
            const int kr = kt * 16 + lq;
            #pragma unroll
            for (int kh = 0; kh < 2; ++kh) {
                s16x8 kf = *(const s16x8*)&Kl[kr * 64 + (((kh * 4 + grp) ^ (lq & 7)) * 8)];
                qk[kt] = __builtin_amdgcn_mfma_f32_16x16x32_bf16(qf[kh], kf, qk[kt], 0, 0, 0);
            }
        }
        // ---- exp + masked sums + P -> LDS (bf16) ----
        #pragma unroll
        for (int kt = 0; kt < 4; ++kt) {
            const int kloc = kt * 16 + lq;
            const int kg = k0 + kloc;
            const float mf0 = Mf[0][kloc], mf1 = Mf[1][kloc];
            const float mf2 = Mf[2][kloc], mf3 = Mf[3][kloc];
            #pragma unroll
            for (int r = 0; r < 4; ++r) {
                const float e = (kg < S) ? __expf(qk[kt][r] * 0.125f) : 0.f;
                sums[0][r] += e;
                sums[1][r] += mf0 * e; sums[2][r] += mf1 * e;
                sums[3][r] += mf2 * e; sums[4][r] += mf3 * e;
                const int q = grp * 4 + r;   // C row -> P row
                Pl[w * 1024 + q * 64 + (((kloc >> 3) ^ (q & 7)) * 8) + (kloc & 7)] = f2bf(e);
            }
        }
        __syncthreads();

        // ---- PV: 5 variants x 4 d-tiles x 2 k-halves ----
        s16x8 pa[5][2];
        #pragma unroll
        for (int h2 = 0; h2 < 2; ++h2) {
            s16x8 ea = *(const s16x8*)&Pl[w * 1024 + lq * 64 + (((h2 * 4 + grp) ^ (lq & 7)) * 8)];
            pa[0][h2] = ea;
            #pragma unroll
            for (int v = 1; v < 5; ++v) {
                s16x8 mm = *(const s16x8*)&Mm[(v - 1) * 64 + (h2 * 4 + grp) * 8];
                pa[v][h2] = ea & mm;
            }
        }
        #pragma unroll
        for (int dt = 0; dt < 4; ++dt) {
            const int dr = dt * 16 + lq;
            #pragma unroll
            for (int h2 = 0; h2 < 2; ++h2) {
                s16x8 vb = *(const s16x8*)&Vl[dr * 64 + (((h2 * 4 + grp) ^ (lq & 7)) * 8)];
                #pragma unroll
                for (int v = 0; v < 5; ++v)
                    acc[v][dt] = __builtin_amdgcn_mfma_f32_16x16x32_bf16(pa[v][h2], vb, acc[v][dt], 0, 0, 0);
            }
        }
    }

    // reduce sums across the 16 column-lanes (q rows live in lanes sharing grp)
    #pragma unroll
    for (int m = 1; m < 16; m <<= 1)
        #pragma unroll
        for (int v = 0; v < 5; ++v)
            #pragma unroll
            for (int r = 0; r < 4; ++r)
                sums[v][r] += __shfl_xor(sums[v][r], m);

    // normalize + store (C layout: row q = grp*4+r, col d = dt*16+lq)
    #pragma unroll
    for (int r = 0; r < 4; ++r) {
        const int q = q0 + w * 16 + grp * 4 + r;
        if (q >= S) continue;
        #pragma unroll
        for (int v = 0; v < 5; ++v) {
            const float inv = 1.0f / sums[v][r];
            float* outp = (v == 0)
                ? out_h    + (size_t)(b * S + q) * D + hh * 64 + lq
                : out_newh + (size_t)((b * NM + v - 1) * S + q) * D + hh * 64 + lq;
            #pragma unroll
            for (int dt = 0; dt < 4; ++dt)
                outp[dt * 16] = acc[v][dt][r] * inv;
        }
    }
}

// ---------------------------------------------------------------------------
// Kernel 3: new_x broadcast copy + img_idx
// ---------------------------------------------------------------------------
__global__ __launch_bounds__(256) void tail_kernel(
    const float* __restrict__ x, float* __restrict__ out_newx,
    float* __restrict__ out_idx)
{
    const int SLAB4  = S * D / 4;
    const int TOTAL4 = B * NM * SLAB4;
    const float4* x4 = (const float4*)x;
    float4* o4 = (float4*)out_newx;
    for (int f = blockIdx.x * blockDim.x + threadIdx.x; f < TOTAL4;
         f += gridDim.x * blockDim.x) {
        const int bm  = f / SLAB4;
        const int rem = f - bm * SLAB4;
        o4[f] = x4[(bm >> 2) * SLAB4 + rem];
    }
    const int idx = blockIdx.x * blockDim.x + threadIdx.x;
    if (idx < B * NM) out_idx[idx] = (float)(idx >> 2);
}

// ---------------------------------------------------------------------------
extern "C" void kernel_launch(void* const* d_in, const int* in_sizes, int n_in,
                              void* d_out, int out_size, void* d_ws, size_t ws_size,
                              hipStream_t stream)
{
    const float* x     = (const float*)d_in[0];
    const int*   masks = (const int*)  d_in[1];
    const float* Wq    = (const float*)d_in[2];
    const float* bq    = (const float*)d_in[3];
    const float* Wk    = (const float*)d_in[4];
    const float* bk    = (const float*)d_in[5];
    const float* Wv    = (const float*)d_in[6];
    const float* bv    = (const float*)d_in[7];

    float* out = (float*)d_out;
    float* out_h    = out;
    float* out_newh = out + OUT_NEWH_OFF;
    float* out_idx  = out + OUT_IDX_OFF;
    float* out_newx = out + OUT_NEWX_OFF;

    unsigned short* Qb = (unsigned short*)d_ws;
    unsigned short* Kb = Qb + BSD;
    unsigned short* Vt = Kb + BSD;   // B*H*64*SP elements

    vt_pad_kernel<<<378, 256, 0, stream>>>(Vt);
    {
        dim3 grid(33, 36);
        qkv_mfma_kernel<<<grid, 256, 0, stream>>>(x, Wq, bq, Wk, bk, Wv, bv,
                                                  Qb, Kb, Vt);
    }
    {
        dim3 grid(17, H, B);
        attn_mfma_kernel<<<grid, 256, 0, stream>>>(Qb, Kb, Vt, masks,
                                                   out_h, out_newh);
    }
    tail_kernel<<<2048, 256, 0, stream>>>(x, out_newx, out_idx);
}

// Round 4
// 99.967 us; speedup vs baseline: 18.7821x; 1.0038x over previous
//
#include <hip/hip_runtime.h>

typedef float f32x4 __attribute__((ext_vector_type(4)));
typedef short s16x8 __attribute__((ext_vector_type(8)));

constexpr int B  = 2;
constexpr int S  = 1025;
constexpr int D  = 768;
constexpr int DD = D * D;
constexpr int H  = 12;
constexpr int NM = 4;
constexpr int ROWS = B * S;              // 2050
constexpr int BSD  = B * S * D;          // 1,574,400
constexpr int SP   = 1088;               // padded S for Vt rows
constexpr int OUT_NEWH_OFF = BSD;
constexpr int OUT_IDX_OFF  = BSD + NM * BSD;
constexpr int OUT_NEWX_OFF = OUT_IDX_OFF + B * NM;

__device__ __forceinline__ unsigned short f2bf(float f) {
    unsigned u = __builtin_bit_cast(unsigned, f);
    u += 0x7FFF + ((u >> 16) & 1);          // RTNE (no NaN inputs here)
    return (unsigned short)(u >> 16);
}

// async global->LDS 16B copy. LDS dest must be wave-uniform base + lane*16;
// swizzled layouts are achieved by pre-swizzling the per-lane GLOBAL source.
__device__ __forceinline__ void gll16(const void* g, void* l) {
    __builtin_amdgcn_global_load_lds(
        (const __attribute__((address_space(1))) void*)g,
        (__attribute__((address_space(3))) void*)l, 16, 0, 0);
}

// ---------------------------------------------------------------------------
// Kernel 0: convert x and Wq/Wk/Wv to bf16 once; zero Vt padding columns.
// xb/Wb live in the out_newx region of d_out (overwritten by tail_kernel last).
// ---------------------------------------------------------------------------
__global__ __launch_bounds__(256) void conv_kernel(
    const float* __restrict__ x, const float* __restrict__ Wq,
    const float* __restrict__ Wk, const float* __restrict__ Wv,
    unsigned short* __restrict__ xb, unsigned short* __restrict__ Wb,
    unsigned short* __restrict__ Vt)
{
    constexpr int NX8 = BSD / 8;        // 196800
    constexpr int NW8 = DD / 8;         // 73728
    constexpr int TOT = NX8 + 3 * NW8;  // 417984
    const int tid = blockIdx.x * 256 + threadIdx.x;
    for (int c = tid; c < TOT; c += gridDim.x * 256) {
        const float* src;
        unsigned short* dst;
        if (c < NX8) { src = x + (size_t)c * 8; dst = xb + (size_t)c * 8; }
        else {
            const int cc = c - NX8;
            const int mt = cc / NW8;
            const int rr = cc - mt * NW8;
            src = ((mt == 0) ? Wq : (mt == 1) ? Wk : Wv) + (size_t)rr * 8;
            dst = Wb + (size_t)mt * DD + (size_t)rr * 8;
        }
        const float4 a = *(const float4*)src;
        const float4 b2 = *(const float4*)(src + 4);
        s16x8 v;
        v[0] = (short)f2bf(a.x);  v[1] = (short)f2bf(a.y);
        v[2] = (short)f2bf(a.z);  v[3] = (short)f2bf(a.w);
        v[4] = (short)f2bf(b2.x); v[5] = (short)f2bf(b2.y);
        v[6] = (short)f2bf(b2.z); v[7] = (short)f2bf(b2.w);
        *(s16x8*)dst = v;
    }
    constexpr int NPADC = SP - S;              // 63
    constexpr int NPAD = B * H * 64 * NPADC;   // 96768
    if (tid < NPAD) {
        const int row = tid / NPADC;
        const int s = S + (tid % NPADC);
        Vt[(size_t)row * SP + s] = 0;
    }
}

// ---------------------------------------------------------------------------
// Kernel 1: QKV projection, bf16 MFMA GEMM, double-buffered gll staging.
// Grid (33 row-tiles of 64, 36 = 12 col-tiles x 3 matrices), 256 threads.
// V stored transposed: Vt[((b*H+h)*64+d)*SP + s].
// ---------------------------------------------------------------------------
__global__ __launch_bounds__(256, 2) void qkv_mfma_kernel(
    const unsigned short* __restrict__ xb, const unsigned short* __restrict__ Wb,
    const float* __restrict__ bq, const float* __restrict__ bk,
    const float* __restrict__ bv,
    unsigned short* __restrict__ Qb, unsigned short* __restrict__ Kb,
    unsigned short* __restrict__ Vt)
{
    __shared__ __align__(16) unsigned short Xs[2][64 * 64];
    __shared__ __align__(16) unsigned short Wl[2][64 * 64];

    const int t = threadIdx.x;
    const int row0 = blockIdx.x * 64;
    const int yy = blockIdx.y;
    const int mt = yy / 12;
    const int col0 = (yy % 12) * 64;
    const float* bias = (mt == 0) ? bq : (mt == 1) ? bk : bv;
    const unsigned short* Wsrc = Wb + (size_t)mt * DD;

    const int w = t >> 6, l = t & 63, lq = l & 15, grp = l >> 4;

    auto stage = [&](int buf, int k0) {
        #pragma unroll
        for (int i = 0; i < 2; ++i) {
            const int slot = i * 256 + t;
            const int r = slot >> 3, cl = slot & 7;
            const int cg = cl ^ (r & 7);
            int row = row0 + r; if (row > ROWS - 1) row = ROWS - 1;
            gll16(xb + (size_t)row * D + k0 + cg * 8, &Xs[buf][slot * 8]);
            gll16(Wsrc + (size_t)(col0 + r) * D + k0 + cg * 8, &Wl[buf][slot * 8]);
        }
    };

    f32x4 acc[4] = {};
    stage(0, 0);

    for (int ks = 0; ks < 12; ++ks) {
        const int cur = ks & 1;
        __syncthreads();                       // buf cur staged (vmcnt drained)
        if (ks + 1 < 12) stage(cur ^ 1, (ks + 1) * 64);

        s16x8 a[2];
        const int xr = w * 16 + lq;
        #pragma unroll
        for (int kh = 0; kh < 2; ++kh)
            a[kh] = *(const s16x8*)&Xs[cur][xr * 64 + (((kh * 4 + grp) ^ (xr & 7)) * 8)];
        #pragma unroll
        for (int nt = 0; nt < 4; ++nt) {
            const int wr = nt * 16 + lq;
            #pragma unroll
            for (int kh = 0; kh < 2; ++kh) {
                s16x8 bfr = *(const s16x8*)&Wl[cur][wr * 64 + (((kh * 4 + grp) ^ (wr & 7)) * 8)];
                acc[nt] = __builtin_amdgcn_mfma_f32_16x16x32_bf16(a[kh], bfr, acc[nt], 0, 0, 0);
            }
        }
    }

    // epilogue: bias add, bf16 store (V transposed)
    #pragma unroll
    for (int nt = 0; nt < 4; ++nt) {
        const int col = col0 + nt * 16 + lq;
        const float bv_ = bias[col];
        #pragma unroll
        for (int r = 0; r < 4; ++r) {
            const int row = row0 + w * 16 + grp * 4 + r;   // C row = (l>>4)*4+reg
            if (row >= ROWS) continue;
            const unsigned short val = f2bf(acc[nt][r] + bv_);
            if (mt == 0)      Qb[(size_t)row * D + col] = val;
            else if (mt == 1) Kb[(size_t)row * D + col] = val;
            else {
                const int bb = (row >= S) ? 1 : 0;
                const int s  = row - bb * S;
                const int hh = col >> 6, dd = col & 63;
                Vt[((size_t)((bb * H + hh) * 64 + dd)) * SP + s] = val;
            }
        }
    }
}

// ---------------------------------------------------------------------------
// Kernel 2: MFMA attention. Block = (32 q-rows, head, batch), 2 waves x 16 q.
// Double-buffered K/V/mask staging via global_load_lds; one barrier per tile;
// loads are in flight across the whole compute phase. Pl is wave-private
// (within-wave ordering only). 5 softmax variants share one exp array;
// masked P fragments are bitwise ANDs. No max-subtraction (scores bounded;
// validated rounds 1-3).
// ---------------------------------------------------------------------------
__global__ __launch_bounds__(128, 2) void attn_mfma_kernel(
    const unsigned short* __restrict__ Qb, const unsigned short* __restrict__ Kb,
    const unsigned short* __restrict__ Vt, const int* __restrict__ masks,
    float* __restrict__ out_h, float* __restrict__ out_newh)
{
    __shared__ __align__(16) unsigned short Kl[2][64 * 64];
    __shared__ __align__(16) unsigned short Vl[2][64 * 64];   // rows=d, cols=k
    __shared__ __align__(16) unsigned short Pl[2][16 * 64];   // per-wave
    __shared__ __align__(16) float          Mf[2][4][64];
    __shared__ __align__(16) unsigned short Mm[2][4 * 64];

    const int t = threadIdx.x;
    const int qt = blockIdx.x, hh = blockIdx.y, b = blockIdx.z;
    const int q0 = qt * 32;
    const int w = t >> 6, l = t & 63, lq = l & 15, grp = l >> 4;

    // Q fragments (A operand; wave's 16 q rows)
    s16x8 qf[2] = {};
    {
        const int row = q0 + w * 16 + lq;
        if (row < S) {
            const unsigned short* p = Qb + (size_t)(b * S + row) * D + hh * 64 + grp * 8;
            qf[0] = *(const s16x8*)(p);
            qf[1] = *(const s16x8*)(p + 32);
        }
    }

    const unsigned short* Kbase = Kb + (size_t)b * S * D + hh * 64;
    const unsigned short* Vbase = Vt + (size_t)(b * H + hh) * 64 * SP;

    auto stage = [&](int buf, int it) {
        const int k0 = it * 64;
        #pragma unroll
        for (int i = 0; i < 4; ++i) {
            const int slot = i * 128 + t;          // lane-linear LDS slots
            const int r = slot >> 3, cl = slot & 7;
            const int cg = cl ^ (r & 7);           // pre-swizzled global source
            int p = k0 + r; if (p > S - 1) p = S - 1;
            gll16(Kbase + (size_t)p * D + cg * 8, &Kl[buf][slot * 8]);
        }
        #pragma unroll
        for (int i = 0; i < 4; ++i) {
            const int slot = i * 128 + t;
            const int r = slot >> 3, cl = slot & 7;
            const int cg = cl ^ (r & 7);
            gll16(Vbase + (size_t)r * SP + k0 + cg * 8, &Vl[buf][slot * 8]);
        }
        #pragma unroll
        for (int j = 0; j < 2; ++j) {
            const int idx = j * 128 + t;
            const int v = idx >> 6, kk = idx & 63;
            const int p = k0 + kk;
            const int m = (p >= 1 && p < S) ? masks[(size_t)(b * NM + v) * (S - 1) + p - 1] : 0;
            Mf[buf][v][kk] = (float)m;
            Mm[buf][v * 64 + kk] = m ? 0xFFFFu : 0u;
        }
    };

    f32x4 acc[5][4] = {};
    float sums[5][4] = {};

    stage(0, 0);

    constexpr int NT = 17;
    for (int it = 0; it < NT; ++it) {
        const int cur = it & 1;
        __syncthreads();                    // drains vmcnt: buf cur complete
        if (it + 1 < NT) stage(cur ^ 1, it + 1);
        const int k0 = it * 64;

        // ---- QK^T (8 MFMA/wave) ----
        f32x4 qk[4] = {};
        #pragma unroll
        for (int kt = 0; kt < 4; ++kt) {
            const int kr = kt * 16 + lq;
            #pragma unroll
            for (int kh = 0; kh < 2; ++kh) {
                s16x8 kf = *(const s16x8*)&Kl[cur][kr * 64 + (((kh * 4 + grp) ^ (kr & 7)) * 8)];
                qk[kt] = __builtin_amdgcn_mfma_f32_16x16x32_bf16(qf[kh], kf, qk[kt], 0, 0, 0);
            }
        }

        // ---- exp + 5 masked sums + P -> wave-private LDS (bf16) ----
        #pragma unroll
        for (int kt = 0; kt < 4; ++kt) {
            const int kloc = kt * 16 + lq;
            const int kg = k0 + kloc;
            const float mf0 = Mf[cur][0][kloc], mf1 = Mf[cur][1][kloc];
            const float mf2 = Mf[cur][2][kloc], mf3 = Mf[cur][3][kloc];
            #pragma unroll
            for (int r = 0; r < 4; ++r) {
                const float e = (kg < S) ? __expf(qk[kt][r] * 0.125f) : 0.f;
                sums[0][r] += e;
                sums[1][r] += mf0 * e; sums[2][r] += mf1 * e;
                sums[3][r] += mf2 * e; sums[4][r] += mf3 * e;
                const int q = grp * 4 + r;   // C row -> P row
                Pl[w][q * 64 + (((kloc >> 3) ^ (q & 7)) * 8) + (kloc & 7)] = f2bf(e);
            }
        }

        // ---- PV (40 MFMA/wave): h2-outer keeps pa at 5 fragments live ----
        #pragma unroll
        for (int h2 = 0; h2 < 2; ++h2) {
            s16x8 ea = *(const s16x8*)&Pl[w][lq * 64 + (((h2 * 4 + grp) ^ (lq & 7)) * 8)];
            s16x8 pa[5];
            pa[0] = ea;
            #pragma unroll
            for (int v = 1; v < 5; ++v) {
                s16x8 mm = *(const s16x8*)&Mm[cur][(v - 1) * 64 + (h2 * 4 + grp) * 8];
                pa[v] = ea & mm;
            }
            #pragma unroll
            for (int dt = 0; dt < 4; ++dt) {
                const int dr = dt * 16 + lq;
                s16x8 vb = *(const s16x8*)&Vl[cur][dr * 64 + (((h2 * 4 + grp) ^ (dr & 7)) * 8)];
                #pragma unroll
                for (int v = 0; v < 5; ++v)
                    acc[v][dt] = __builtin_amdgcn_mfma_f32_16x16x32_bf16(pa[v], vb, acc[v][dt], 0, 0, 0);
            }
        }
    }

    // reduce per-q sums across the 16 column-lanes
    #pragma unroll
    for (int m = 1; m < 16; m <<= 1)
        #pragma unroll
        for (int v = 0; v < 5; ++v)
            #pragma unroll
            for (int r = 0; r < 4; ++r)
                sums[v][r] += __shfl_xor(sums[v][r], m);

    // normalize + store (C layout: row q = grp*4+r, col d = dt*16+lq)
    #pragma unroll
    for (int r = 0; r < 4; ++r) {
        const int q = q0 + w * 16 + grp * 4 + r;
        if (q >= S) continue;
        #pragma unroll
        for (int v = 0; v < 5; ++v) {
            const float inv = 1.0f / sums[v][r];
            float* outp = (v == 0)
                ? out_h    + (size_t)(b * S + q) * D + hh * 64 + lq
                : out_newh + (size_t)((b * NM + v - 1) * S + q) * D + hh * 64 + lq;
            #pragma unroll
            for (int dt = 0; dt < 4; ++dt)
                outp[dt * 16] = acc[v][dt][r] * inv;
        }
    }
}

// ---------------------------------------------------------------------------
// Kernel 3: new_x broadcast copy + img_idx (runs LAST: overwrites the
// out_newx region that conv/qkv used as bf16 scratch).
// ---------------------------------------------------------------------------
__global__ __launch_bounds__(256) void tail_kernel(
    const float* __restrict__ x, float* __restrict__ out_newx,
    float* __restrict__ out_idx)
{
    const int SLAB4  = S * D / 4;
    const int TOTAL4 = B * NM * SLAB4;
    const float4* x4 = (const float4*)x;
    float4* o4 = (float4*)out_newx;
    for (int f = blockIdx.x * blockDim.x + threadIdx.x; f < TOTAL4;
         f += gridDim.x * blockDim.x) {
        const int bm  = f / SLAB4;
        const int rem = f - bm * SLAB4;
        o4[f] = x4[(bm >> 2) * SLAB4 + rem];
    }
    const int idx = blockIdx.x * blockDim.x + threadIdx.x;
    if (idx < B * NM) out_idx[idx] = (float)(idx >> 2);
}

// ---------------------------------------------------------------------------
extern "C" void kernel_launch(void* const* d_in, const int* in_sizes, int n_in,
                              void* d_out, int out_size, void* d_ws, size_t ws_size,
                              hipStream_t stream)
{
    const float* x     = (const float*)d_in[0];
    const int*   masks = (const int*)  d_in[1];
    const float* Wq    = (const float*)d_in[2];
    const float* bq    = (const float*)d_in[3];
    const float* Wk    = (const float*)d_in[4];
    const float* bk    = (const float*)d_in[5];
    const float* Wv    = (const float*)d_in[6];
    const float* bv    = (const float*)d_in[7];

    float* out = (float*)d_out;
    float* out_h    = out;
    float* out_newh = out + OUT_NEWH_OFF;
    float* out_idx  = out + OUT_IDX_OFF;
    float* out_newx = out + OUT_NEWX_OFF;

    unsigned short* Qb = (unsigned short*)d_ws;
    unsigned short* Kb = Qb + BSD;
    unsigned short* Vt = Kb + BSD;           // B*H*64*SP elements

    // bf16 scratch aliased into the out_newx region (rewritten by tail_kernel)
    unsigned short* xb = (unsigned short*)out_newx;
    unsigned short* Wb = xb + BSD;

    conv_kernel<<<1634, 256, 0, stream>>>(x, Wq, Wk, Wv, xb, Wb, Vt);
    {
        dim3 grid(33, 36);
        qkv_mfma_kernel<<<grid, 256, 0, stream>>>(xb, Wb, bq, bk, bv, Qb, Kb, Vt);
    }
    {
        dim3 grid(33, H, B);
        attn_mfma_kernel<<<grid, 128, 0, stream>>>(Qb, Kb, Vt, masks,
                                                   out_h, out_newh);
    }
    tail_kernel<<<2048, 256, 0, stream>>>(x, out_newx, out_idx);
}